// Round 7
// baseline (150.574 us; speedup 1.0000x reference)
//
#include <hip/hip_runtime.h>

// Problem dims (AdditiveAttention_56865366999388)
#define NB 4
#define NQL 512   // query length
#define ML 512    // key/value length
#define DDIM 256  // DQ == DK == DV
#define HDIM 256  // H

static constexpr float TWO_LOG2E = 2.8853900817779268f; // 2*log2(e)
static constexpr float LOG2E     = 1.4426950408889634f;

#define SB() __builtin_amdgcn_sched_barrier(0)

// ---------------------------------------------------------------------------
// Kernel 1: projection + exp. All-global (no LDS); SB-fenced double-buffered
// register pipeline. 32l x 64h tile, 256 thr, 2l x 4h per thread, chunk = 4d
// (2 X b128 + 4 W b128 per 32 fma). grid 512 (1D) = 2 blocks/CU = 2 w/SIMD.
// idx = b | which<<2 | lt<<3 | ht<<7 ; idx&7 = (b,which) per-XCD pin.
// ---------------------------------------------------------------------------
#define PJ_LOAD(Xr, Wr, c)                                          \
    {                                                               \
        const int d_ = (c) * 4;                                     \
        Xr[0] = *(const float4*)(xr0 + d_);                         \
        Xr[1] = *(const float4*)(xr1 + d_);                         \
        Wr[0] = *(const float4*)(wc + (size_t)(d_ + 0) * HDIM);     \
        Wr[1] = *(const float4*)(wc + (size_t)(d_ + 1) * HDIM);     \
        Wr[2] = *(const float4*)(wc + (size_t)(d_ + 2) * HDIM);     \
        Wr[3] = *(const float4*)(wc + (size_t)(d_ + 3) * HDIM);     \
    }

#define PJ_FMA(Xr, Wr, comp, r)                                     \
    acc[0][0] = fmaf(Xr[0].comp, Wr[r].x, acc[0][0]);               \
    acc[0][1] = fmaf(Xr[0].comp, Wr[r].y, acc[0][1]);               \
    acc[0][2] = fmaf(Xr[0].comp, Wr[r].z, acc[0][2]);               \
    acc[0][3] = fmaf(Xr[0].comp, Wr[r].w, acc[0][3]);               \
    acc[1][0] = fmaf(Xr[1].comp, Wr[r].x, acc[1][0]);               \
    acc[1][1] = fmaf(Xr[1].comp, Wr[r].y, acc[1][1]);               \
    acc[1][2] = fmaf(Xr[1].comp, Wr[r].z, acc[1][2]);               \
    acc[1][3] = fmaf(Xr[1].comp, Wr[r].w, acc[1][3]);

#define PJ_COMP(Xr, Wr)                                             \
    PJ_FMA(Xr, Wr, x, 0) PJ_FMA(Xr, Wr, y, 1)                       \
    PJ_FMA(Xr, Wr, z, 2) PJ_FMA(Xr, Wr, w, 3)

__global__ __launch_bounds__(256) void proj_kernel(
    const float* __restrict__ q_src, const float* __restrict__ k_src,
    const float* __restrict__ Wq,    const float* __restrict__ Wk,
    float* __restrict__ EqT,         float* __restrict__ EkT)
{
    const int idx   = blockIdx.x;
    const int b     = idx & 3;
    const int which = (idx >> 2) & 1;
    const int lt    = (idx >> 3) & 15;
    const int ht    = idx >> 7;
    const float* __restrict__ src = which ? k_src : q_src;
    const float* __restrict__ W   = which ? Wk : Wq;
    float* __restrict__ outT      = which ? EkT : EqT;

    const int l0 = lt * 32, h0 = ht * 64;
    const int t  = threadIdx.x;
    const int tx = t & 15;   // h group (4 each)
    const int ty = t >> 4;   // l group (2 each), 0..15

    const float* xr0 = &src[(size_t)(b * NQL + l0 + ty * 2) * DDIM];
    const float* xr1 = xr0 + DDIM;
    const float* wc  = &W[h0 + tx * 4];

    float4 XA[2], WA[4], XB[2], WB[4];
    float acc[2][4] = {};

    // 64 chunks of 4 d, double-buffered + fenced.
    PJ_LOAD(XA, WA, 0)
    SB();
    for (int v = 0; v < 31; ++v) {
        PJ_LOAD(XB, WB, 2 * v + 1)
        SB();
        PJ_COMP(XA, WA)
        SB();
        PJ_LOAD(XA, WA, 2 * v + 2)
        SB();
        PJ_COMP(XB, WB)
        SB();
    }
    PJ_LOAD(XB, WB, 63)
    SB();
    PJ_COMP(XA, WA)      // chunk 62
    SB();
    PJ_COMP(XB, WB)      // chunk 63

    #pragma unroll
    for (int j = 0; j < 4; ++j) {
        float2 o;   // e^{2*proj}, stored h-major: [b][h][l]
        o.x = __builtin_amdgcn_exp2f(acc[0][j] * TWO_LOG2E);
        o.y = __builtin_amdgcn_exp2f(acc[1][j] * TWO_LOG2E);
        *(float2*)&outT[(size_t)(b * HDIM + h0 + tx * 4 + j) * NQL + l0 + ty * 2] = o;
    }
}

// ---------------------------------------------------------------------------
// Kernel 2: scores + exp + partial row sums.
// KEY CHANGE vs r6: m-tile 64->32 with 4n x 2m per thread, grid 256->512
// (2 blocks/CU of 512 thr = 16 waves/CU = 4 waves/SIMD). Per-CU-hh LDS
// 304 cy < VALU wall 320 cy: still VALU-bound, 2x latency hiding of r6.
// h-split kept: waves 0-3 sum h in [0,128), waves 4-7 in [128,256);
// halves combined through LDS in the epilogue.
//   tanh(q+k) = 1 - 2/(e^{2q}e^{2k}+1);  S = sum_h Wv[h] - 2*sum_h Wv[h]/a,
//   a = fma(Eq,Ek,1). rcp paired across n. P = exp(S) unnorm (|S| <= ~13).
// 64n x 32m tile, grid 512 (1D): idx = b | mt<<2 | nt<<6; idx&7 = (b,mt&1)
// pins per-XCD working set Eq[b] 512KB + half Ek[b] 256KB (L2-fit).
// ---------------------------------------------------------------------------
#define SC_M(jm, km)                                         \
    {                                                        \
        float a0 = fmaf(q4.x, km, 1.0f);                     \
        float a1 = fmaf(q4.y, km, 1.0f);                     \
        float a2 = fmaf(q4.z, km, 1.0f);                     \
        float a3 = fmaf(q4.w, km, 1.0f);                     \
        float r01 = __builtin_amdgcn_rcpf(a0 * a1);          \
        float r23 = __builtin_amdgcn_rcpf(a2 * a3);          \
        float t01 = nw2 * r01, t23 = nw2 * r23;              \
        acc[0][jm] = fmaf(t01, a1, acc[0][jm]);              \
        acc[1][jm] = fmaf(t01, a0, acc[1][jm]);              \
        acc[2][jm] = fmaf(t23, a3, acc[2][jm]);              \
        acc[3][jm] = fmaf(t23, a2, acc[3][jm]);              \
    }

__global__ __launch_bounds__(512) void scores_kernel(
    const float* __restrict__ EqT, const float* __restrict__ EkT,
    const float* __restrict__ Wv, float* __restrict__ P,
    float* __restrict__ Spart)
{
    const int idx = blockIdx.x;
    const int b   = idx & 3;
    const int mt  = (idx >> 2) & 15;   // 16 m-tiles of 32
    const int nt  = idx >> 6;          // 8 n-tiles of 64
    const int m0  = mt * 32, n0 = nt * 64;
    const int t    = threadIdx.x;
    const int wid  = t >> 6;
    const int g    = wid >> 2;               // h-half: waves 0-3 -> 0, 4-7 -> 1
    const int tg   = (wid & 3) * 64 + (t & 63);  // 0..255 within group
    const int tx   = tg & 15;   // m pair (2 each)
    const int ty   = tg >> 4;   // n quad (4 each)

    __shared__ float sQ[2][2][16][68];   // [g][buf][hh][nn] 16h x 64n (+pad)
    __shared__ float sK[2][2][16][36];   // [g][buf][hh][mm] 16h x 32m (+pad)

    const int rq = tg >> 4, cq = tg & 15;   // q stage: 16 rows x 16 grps(4)
    const int rk = tg >> 3, ck = tg & 7;    // k stage (tg<128): 16 rows x 8 grps(4)

    const float* qbase = &EqT[(size_t)(b * HDIM + g * 128) * NQL + n0];
    const float* kbase = &EkT[(size_t)(b * HDIM + g * 128) * ML + m0];

    // preload chunk 0 (16 h rows) into staging regs
    float4 qv = *(const float4*)(qbase + (size_t)rq * NQL + cq * 4);
    float4 kv = {0.f, 0.f, 0.f, 0.f};
    if (tg < 128) kv = *(const float4*)(kbase + (size_t)rk * ML + ck * 4);

    float acc[4][2] = {};
    int cur = 0;

    for (int c = 0; c < 8; ++c) {   // 8 chunks of 16 hh (this half's 128 h)
        *(float4*)&sQ[g][cur][rq][cq * 4] = qv;
        if (tg < 128) *(float4*)&sK[g][cur][rk][ck * 4] = kv;
        __syncthreads();
        if (c < 7) {   // prefetch next chunk; latency hides under compute
            qv = *(const float4*)(qbase + (size_t)((c + 1) * 16 + rq) * NQL + cq * 4);
            if (tg < 128)
                kv = *(const float4*)(kbase + (size_t)((c + 1) * 16 + rk) * ML + ck * 4);
        }
        const float* wvp = Wv + g * 128 + c * 16;   // uniform -> scalar loads
        #pragma unroll
        for (int hh = 0; hh < 16; ++hh) {
            float4 q4 = *(const float4*)&sQ[g][cur][hh][ty * 4];
            float2 k2 = *(const float2*)&sK[g][cur][hh][tx * 2];
            const float nw2 = -2.0f * wvp[hh];
            SC_M(0, k2.x) SC_M(1, k2.y)
        }
        cur ^= 1;
    }

    // combine the two h-halves through LDS (reuse sQ region, 8 KB needed)
    __syncthreads();
    float* sred = &sQ[0][0][0][0];
    if (g == 1) {
        #pragma unroll
        for (int i = 0; i < 4; ++i)
            #pragma unroll
            for (int j = 0; j < 2; ++j)
                sred[(i * 2 + j) * 256 + tg] = acc[i][j];
    }
    __syncthreads();
    if (g == 0) {
        float swv = 0.f;   // sum of all Wv: uniform -> scalar math
        #pragma unroll 8
        for (int i = 0; i < HDIM; i += 4) {
            float4 w = *(const float4*)(Wv + i);
            swv += (w.x + w.y) + (w.z + w.w);
        }
        float rsum[4];
        #pragma unroll
        for (int i = 0; i < 4; ++i) {
            float2 p;
            p.x = __builtin_amdgcn_exp2f((swv + acc[i][0] + sred[(i * 2 + 0) * 256 + tg]) * LOG2E);
            p.y = __builtin_amdgcn_exp2f((swv + acc[i][1] + sred[(i * 2 + 1) * 256 + tg]) * LOG2E);
            *(float2*)&P[(size_t)(b * NQL + n0 + ty * 4 + i) * ML + m0 + tx * 2] = p;
            rsum[i] = p.x + p.y;
        }
        #pragma unroll
        for (int off = 1; off < 16; off <<= 1) {  // reduce over the 16 tx lanes
            #pragma unroll
            for (int i = 0; i < 4; ++i) rsum[i] += __shfl_xor(rsum[i], off);
        }
        if (tx == 0) {
            #pragma unroll
            for (int i = 0; i < 4; ++i)
                Spart[(size_t)(mt * NB + b) * NQL + n0 + ty * 4 + i] = rsum[i];
        }
    }
}

// ---------------------------------------------------------------------------
// Kernel 3: out[b][n][v] = (sum_m P[b][n][m] * V[b][m][v]) / rowsum[b][n]
// KEY CHANGE vs r6: n-tile 16->8, grid 512->1024 = 4 blocks/CU of 256 thr
// = 16 waves/CU = 4 waves/SIMD. Per-thread 2n x 4v, m-split 4 across the
// block's 4 waves (128 m each), chunk = 4 m (2 P b128 + 4 V b128, 32 fma),
// SB-fenced dbuf. LDS only for the 3->1 epilogue reduce + sInv.
// grid idx = b | vt<<2 | nt<<4 ; idx&7 = (b, vt&1) per-XCD pin.
// ---------------------------------------------------------------------------
#define AV_ONE(PSb, VSb, i, r, comp)                                 \
    acc[i][0] = fmaf(PSb[i].comp, VSb[r].x, acc[i][0]);              \
    acc[i][1] = fmaf(PSb[i].comp, VSb[r].y, acc[i][1]);              \
    acc[i][2] = fmaf(PSb[i].comp, VSb[r].z, acc[i][2]);              \
    acc[i][3] = fmaf(PSb[i].comp, VSb[r].w, acc[i][3]);
#define AV_RR(PSb, VSb, r, comp)                                     \
    AV_ONE(PSb, VSb, 0, r, comp) AV_ONE(PSb, VSb, 1, r, comp)
#define AV_COMP(PSb, VSb)                                            \
    AV_RR(PSb, VSb, 0, x) AV_RR(PSb, VSb, 1, y)                      \
    AV_RR(PSb, VSb, 2, z) AV_RR(PSb, VSb, 3, w)

#define AV_LOAD(PSb, VSb, c)                                              \
    {                                                                     \
        const int mm_ = (c) * 4;                                          \
        PSb[0] = *(const float4*)(pbase + mm_);                           \
        PSb[1] = *(const float4*)(pbase + ML + mm_);                      \
        _Pragma("unroll")                                                 \
        for (int r_ = 0; r_ < 4; ++r_)                                    \
            VSb[r_] = *(const float4*)(vbase + (size_t)(mm_ + r_) * DDIM);\
    }

__global__ __launch_bounds__(256) void av_kernel(
    const float* __restrict__ P, const float* __restrict__ Spart,
    const float* __restrict__ V, float* __restrict__ O)
{
    const int idx = blockIdx.x;
    const int b   = idx & 3;
    const int vt  = (idx >> 2) & 3;
    const int nt  = idx >> 4;          // 0..63
    const int v0  = vt * 64, n0 = nt * 8;
    const int t    = threadIdx.x;
    const int lane = t & 63;
    const int wid  = t >> 6;    // m-quarter selector (4 waves)
    const int tx   = lane & 15; // v group (4 each)
    const int tn   = lane >> 4; // n pair (2 rows each), 0..3

    __shared__ float sInv[8];
    __shared__ float sRed[3][8][64];   // 6 KB epilogue reduce

    if (t < 8) {   // softmax denominators from the 16 scores partials
        float s = 0.f;
        #pragma unroll
        for (int mt = 0; mt < 16; ++mt)
            s += Spart[(size_t)(mt * NB + b) * NQL + n0 + t];
        sInv[t] = 1.0f / s;
    }

    const float* pbase = &P[(size_t)(b * NQL + n0 + tn * 2) * ML + wid * 128];
    const float* vbase = &V[(size_t)(b * ML + wid * 128) * DDIM + v0 + tx * 4];

    float4 PA[2], VA[4];     // buffer A: P rows = 2 n, V rows = 4 m
    float4 PB[2], VB[4];     // buffer B
    float acc[2][4] = {};

    // 32 chunks of 4 m. Double-buffered, fenced.
    AV_LOAD(PA, VA, 0)
    SB();
    for (int v = 0; v < 15; ++v) {
        AV_LOAD(PB, VB, 2 * v + 1)
        SB();
        AV_COMP(PA, VA)
        SB();
        AV_LOAD(PA, VA, 2 * v + 2)
        SB();
        AV_COMP(PB, VB)
        SB();
    }
    AV_LOAD(PB, VB, 31)
    SB();
    AV_COMP(PA, VA)          // chunk 30
    SB();
    AV_COMP(PB, VB)          // chunk 31

    __syncthreads();
    if (wid != 0) {
        #pragma unroll
        for (int i = 0; i < 2; ++i) {
            float4 r = {acc[i][0], acc[i][1], acc[i][2], acc[i][3]};
            *(float4*)&sRed[wid - 1][tn * 2 + i][tx * 4] = r;
        }
    }
    __syncthreads();
    if (wid == 0) {
        #pragma unroll
        for (int i = 0; i < 2; ++i) {
            float4 r1 = *(const float4*)&sRed[0][tn * 2 + i][tx * 4];
            float4 r2 = *(const float4*)&sRed[1][tn * 2 + i][tx * 4];
            float4 r3 = *(const float4*)&sRed[2][tn * 2 + i][tx * 4];
            const float inv = sInv[tn * 2 + i];
            float4 o;
            o.x = (acc[i][0] + r1.x + r2.x + r3.x) * inv;
            o.y = (acc[i][1] + r1.y + r2.y + r3.y) * inv;
            o.z = (acc[i][2] + r1.z + r2.z + r3.z) * inv;
            o.w = (acc[i][3] + r1.w + r2.w + r3.w) * inv;
            *(float4*)&O[(size_t)(b * NQL + n0 + tn * 2 + i) * DDIM + v0 + tx * 4] = o;
        }
    }
}

// ---------------------------------------------------------------------------
extern "C" void kernel_launch(void* const* d_in, const int* in_sizes, int n_in,
                              void* d_out, int out_size, void* d_ws, size_t ws_size,
                              hipStream_t stream)
{
    const float* query = (const float*)d_in[0]; // (4,512,256)
    const float* key   = (const float*)d_in[1]; // (4,512,256)
    const float* value = (const float*)d_in[2]; // (4,512,256)
    const float* Wq    = (const float*)d_in[3]; // (256,256)
    const float* Wk    = (const float*)d_in[4]; // (256,256)
    const float* Wv    = (const float*)d_in[5]; // (256,)
    float* out = (float*)d_out;                 // (4,512,256)

    // workspace layout (fp32): EqT 2MB | EkT 2MB | P 4MB | Spart 128KB
    float* EqT   = (float*)d_ws;                      // [4][256][512]
    float* EkT   = EqT + (size_t)NB * HDIM * NQL;     // [4][256][512]
    float* P     = EkT + (size_t)NB * HDIM * ML;      // [4][512][512] (= exp(S))
    float* Spart = P + (size_t)NB * NQL * ML;         // [16][4][512] partial row sums

    proj_kernel<<<dim3(512), 256, 0, stream>>>(query, key, Wq, Wk, EqT, EkT);
    scores_kernel<<<dim3(512), 512, 0, stream>>>(EqT, EkT, Wv, P, Spart);
    av_kernel<<<dim3(1024), 256, 0, stream>>>(P, Spart, value, out);
}

// Round 8
// 133.578 us; speedup vs baseline: 1.1272x; 1.1272x over previous
//
#include <hip/hip_runtime.h>
#include <hip/hip_bf16.h>

// Problem dims (AdditiveAttention_56865366999388)
#define NB 4
#define NQL 512   // query length
#define ML 512    // key/value length
#define DDIM 256  // DQ == DK == DV
#define HDIM 256  // H

static constexpr float TWO_LOG2E = 2.8853900817779268f; // 2*log2(e)
static constexpr float LOG2E     = 1.4426950408889634f;

// ---------------------------------------------------------------------------
// Kernel 1: projection + exp.  (byte-identical to the 133.7us baseline)
//   EqT[b][h][l] = exp2( TWO_LOG2E * sum_d q_src[b][l][d]*Wq[d][h] )  (= e^{2q})
//   EkT likewise. Stored h-major so scores kernel reads contiguous l rows.
// grid: (l_tiles=16, h_tiles=4, z=8: z>>2 which, z&3 b). block 256.
// 32l x 64h tile, 2l x 4h per thread.
// ---------------------------------------------------------------------------
__global__ __launch_bounds__(256) void proj_kernel(
    const float* __restrict__ q_src, const float* __restrict__ k_src,
    const float* __restrict__ Wq,    const float* __restrict__ Wk,
    float* __restrict__ EqT,         float* __restrict__ EkT)
{
    const int z = blockIdx.z;
    const int b = z & 3;
    const int which = z >> 2;
    const float* __restrict__ src  = which ? k_src : q_src;
    const float* __restrict__ W    = which ? Wk    : Wq;
    float* __restrict__       outT = which ? EkT   : EqT;

    const int l0 = blockIdx.x * 32;
    const int h0 = blockIdx.y * 64;
    const int t  = threadIdx.x;
    const int tx = t & 15;   // h group (4 each)
    const int ty = t >> 4;   // l (2 each)

    __shared__ float sX[32][36];   // [dd][ll]  32d x 32l
    __shared__ float sW[32][68];   // [dd][hh]  32d x 64h

    float acc[2][4];
    #pragma unroll
    for (int i = 0; i < 2; i++)
        #pragma unroll
        for (int j = 0; j < 4; j++) acc[i][j] = 0.f;

    const int llA = t >> 3, dgA = t & 7;   // X: 32 l rows x 8 d-groups(4)
    const int ddB = t >> 3, hgB = t & 7;   // W: 32 d rows x 8 h-groups(8)

    for (int d0 = 0; d0 < DDIM; d0 += 32) {
        float4 xv = *(const float4*)&src[(size_t)(b * NQL + l0 + llA) * DDIM + d0 + dgA * 4];
        const float* wrow = &W[(size_t)(d0 + ddB) * HDIM + h0 + hgB * 8];
        float4 wa = ((const float4*)wrow)[0];
        float4 wb = ((const float4*)wrow)[1];
        __syncthreads();
        sX[dgA * 4 + 0][llA] = xv.x;
        sX[dgA * 4 + 1][llA] = xv.y;
        sX[dgA * 4 + 2][llA] = xv.z;
        sX[dgA * 4 + 3][llA] = xv.w;
        *(float4*)&sW[ddB][hgB * 8]     = wa;
        *(float4*)&sW[ddB][hgB * 8 + 4] = wb;
        __syncthreads();
        #pragma unroll
        for (int dd = 0; dd < 32; dd++) {
            float4 w4 = *(const float4*)&sW[dd][tx * 4];
            float2 x2 = *(const float2*)&sX[dd][ty * 2];
            acc[0][0] = fmaf(x2.x, w4.x, acc[0][0]);
            acc[0][1] = fmaf(x2.x, w4.y, acc[0][1]);
            acc[0][2] = fmaf(x2.x, w4.z, acc[0][2]);
            acc[0][3] = fmaf(x2.x, w4.w, acc[0][3]);
            acc[1][0] = fmaf(x2.y, w4.x, acc[1][0]);
            acc[1][1] = fmaf(x2.y, w4.y, acc[1][1]);
            acc[1][2] = fmaf(x2.y, w4.z, acc[1][2]);
            acc[1][3] = fmaf(x2.y, w4.w, acc[1][3]);
        }
    }

    #pragma unroll
    for (int j = 0; j < 4; j++) {
        float2 o;
        o.x = __builtin_amdgcn_exp2f(acc[0][j] * TWO_LOG2E);
        o.y = __builtin_amdgcn_exp2f(acc[1][j] * TWO_LOG2E);
        *(float2*)&outT[(size_t)(b * HDIM + h0 + tx * 4 + j) * NQL + l0 + ty * 2] = o;
    }
}

// ---------------------------------------------------------------------------
// Kernel 2: scores + exp + partial row sums.  (baseline scores kernel with
// the separate softmax pass folded into the epilogue — the ONE change)
//   tanh(q+k) = 1 - 2/(e^{2q}e^{2k}+1);  S = sum_h Wv[h] - sum_h 2*Wv[h]/a,
//   a = fma(Eq,Ek,1).  Paired reciprocal: rcp(a0*a1) then unpair via mul.
//   P = exp(S) unnormalized (|S| <= sum|Wv| ~ 13: e^13 ~ 4e5, fp32-safe,
//   rowsum <= 512*4e5 ~ 2e8, fp32-safe). Partial row sums -> Spart[mt][b][n].
// grid: (m_tiles=16, n_tiles=16, b=4) = 1024 blocks (4/CU). block 256.
// 32x32 tile, 2n x 2m per thread.
// ---------------------------------------------------------------------------
__global__ __launch_bounds__(256) void scores_kernel(
    const float* __restrict__ EqT, const float* __restrict__ EkT,
    const float* __restrict__ Wv, float* __restrict__ P,
    float* __restrict__ Spart)
{
    const int b  = blockIdx.z;
    const int mt = blockIdx.x;
    const int m0 = mt * 32;
    const int n0 = blockIdx.y * 32;
    const int t  = threadIdx.x;
    const int tx = t & 15;   // m (2 each)
    const int ty = t >> 4;   // n (2 each)

    __shared__ float sQ[32][36];   // [hh][nn]
    __shared__ float sK[32][36];   // [hh][mm]
    __shared__ float sWV[32];

    float acc00 = 0.f, acc01 = 0.f, acc10 = 0.f, acc11 = 0.f;
    float swv = 0.f;

    const int hhA = t >> 3, cgA = t & 7;  // staging: 32 h rows x 8 col-groups(4)

    for (int h0 = 0; h0 < HDIM; h0 += 32) {
        float4 qv = *(const float4*)&EqT[(size_t)(b * HDIM + h0 + hhA) * NQL + n0 + cgA * 4];
        float4 kv = *(const float4*)&EkT[(size_t)(b * HDIM + h0 + hhA) * ML  + m0 + cgA * 4];
        float wv_ld = (t < 32) ? Wv[h0 + t] : 0.f;
        __syncthreads();
        *(float4*)&sQ[hhA][cgA * 4] = qv;
        *(float4*)&sK[hhA][cgA * 4] = kv;
        if (t < 32) sWV[t] = wv_ld;
        __syncthreads();
        #pragma unroll 8
        for (int hh = 0; hh < 32; hh++) {
            float2 q2 = *(const float2*)&sQ[hh][ty * 2];
            float2 k2 = *(const float2*)&sK[hh][tx * 2];
            float wv = sWV[hh];
            swv += wv;
            const float nw2 = -2.0f * wv;
            float a00 = fmaf(q2.x, k2.x, 1.0f);   // e^{2(q+k)} + 1
            float a01 = fmaf(q2.x, k2.y, 1.0f);
            float a10 = fmaf(q2.y, k2.x, 1.0f);
            float a11 = fmaf(q2.y, k2.y, 1.0f);
            float r0 = __builtin_amdgcn_rcpf(a00 * a01);
            float r1 = __builtin_amdgcn_rcpf(a10 * a11);
            acc00 = fmaf(nw2, r0 * a01, acc00);
            acc01 = fmaf(nw2, r0 * a00, acc01);
            acc10 = fmaf(nw2, r1 * a11, acc10);
            acc11 = fmaf(nw2, r1 * a10, acc11);
        }
    }

    // epilogue (changed vs baseline): P = exp(S) + per-block partial rowsums
    float2 o0, o1;
    o0.x = __builtin_amdgcn_exp2f((swv + acc00) * LOG2E);
    o0.y = __builtin_amdgcn_exp2f((swv + acc01) * LOG2E);
    o1.x = __builtin_amdgcn_exp2f((swv + acc10) * LOG2E);
    o1.y = __builtin_amdgcn_exp2f((swv + acc11) * LOG2E);
    *(float2*)&P[(size_t)(b * NQL + n0 + ty * 2 + 0) * ML + m0 + tx * 2] = o0;
    *(float2*)&P[(size_t)(b * NQL + n0 + ty * 2 + 1) * ML + m0 + tx * 2] = o1;

    float rs0 = o0.x + o0.y;               // this thread's 2 m for n-row 0
    float rs1 = o1.x + o1.y;               // ... n-row 1
    #pragma unroll
    for (int off = 1; off < 16; off <<= 1) {   // reduce across the 16 tx lanes
        rs0 += __shfl_xor(rs0, off);
        rs1 += __shfl_xor(rs1, off);
    }
    if (tx == 0) {
        Spart[(size_t)(mt * NB + b) * NQL + n0 + ty * 2 + 0] = rs0;
        Spart[(size_t)(mt * NB + b) * NQL + n0 + ty * 2 + 1] = rs1;
    }
}

// ---------------------------------------------------------------------------
// Kernel 3: out[b][n][v] = (sum_m P[b][n][m] * V[b][m][v]) / rowsum[b][n]
// (baseline av kernel; only change: sInv from Spart, multiplied in epilogue)
// grid: (v_tiles=4, n_tiles=32, b=4) = 512 blocks. block 256.
// 16n x 64v tile, 1n x 4v per thread.
// ---------------------------------------------------------------------------
__global__ __launch_bounds__(256) void av_kernel(
    const float* __restrict__ A, const float* __restrict__ Spart,
    const float* __restrict__ V, float* __restrict__ O)
{
    const int b  = blockIdx.z;
    const int v0 = blockIdx.x * 64;
    const int n0 = blockIdx.y * 16;
    const int t  = threadIdx.x;
    const int tx = t & 15;   // v group (4 each)
    const int ty = t >> 4;   // n (1 each)

    __shared__ float sA[32][20];  // [mm][nn] 32m x 16n
    __shared__ float sV[32][68];  // [mm][vv] 32m x 64v
    __shared__ float sInv[16];

    if (t < 16) {   // softmax denominators from the 16 scores partials
        float s = 0.f;
        #pragma unroll
        for (int mt = 0; mt < 16; ++mt)
            s += Spart[(size_t)(mt * NB + b) * NQL + n0 + t];
        sInv[t] = 1.0f / s;
    }

    float4 acc = {0.f, 0.f, 0.f, 0.f};

    const int nnA = t >> 4, mgA = t & 15;  // A: 16 n rows x 16 m-groups(2)
    const int mmB = t >> 3, vgB = t & 7;   // V: 32 m rows x 8 v-groups(8)

    for (int m0 = 0; m0 < ML; m0 += 32) {
        float2 av = *(const float2*)&A[(size_t)(b * NQL + n0 + nnA) * ML + m0 + mgA * 2];
        const float* vrow = &V[(size_t)(b * ML + m0 + mmB) * DDIM + v0 + vgB * 8];
        float4 va = ((const float4*)vrow)[0];
        float4 vb = ((const float4*)vrow)[1];
        __syncthreads();
        sA[mgA * 2 + 0][nnA] = av.x;
        sA[mgA * 2 + 1][nnA] = av.y;
        *(float4*)&sV[mmB][vgB * 8]     = va;
        *(float4*)&sV[mmB][vgB * 8 + 4] = vb;
        __syncthreads();
        #pragma unroll
        for (int mm = 0; mm < 32; mm++) {
            float a = sA[mm][ty];
            float4 v4 = *(const float4*)&sV[mm][tx * 4];
            acc.x = fmaf(a, v4.x, acc.x);
            acc.y = fmaf(a, v4.y, acc.y);
            acc.z = fmaf(a, v4.z, acc.z);
            acc.w = fmaf(a, v4.w, acc.w);
        }
    }

    const float inv = sInv[ty];
    float4 o;
    o.x = acc.x * inv;
    o.y = acc.y * inv;
    o.z = acc.z * inv;
    o.w = acc.w * inv;
    *(float4*)&O[(size_t)(b * NQL + n0 + ty) * DDIM + v0 + tx * 4] = o;
}

// ---------------------------------------------------------------------------
extern "C" void kernel_launch(void* const* d_in, const int* in_sizes, int n_in,
                              void* d_out, int out_size, void* d_ws, size_t ws_size,
                              hipStream_t stream)
{
    const float* query = (const float*)d_in[0]; // (4,512,256)
    const float* key   = (const float*)d_in[1]; // (4,512,256)
    const float* value = (const float*)d_in[2]; // (4,512,256)
    const float* Wq    = (const float*)d_in[3]; // (256,256)
    const float* Wk    = (const float*)d_in[4]; // (256,256)
    const float* Wv    = (const float*)d_in[5]; // (256,)
    float* out = (float*)d_out;                 // (4,512,256)

    // workspace layout (fp32): EqT 2MB | EkT 2MB | P 4MB | Spart 128KB
    float* EqT   = (float*)d_ws;                      // [4][256][512]
    float* EkT   = EqT + (size_t)NB * HDIM * NQL;     // [4][256][512]
    float* P     = EkT + (size_t)NB * HDIM * ML;      // [4][512][512] (= exp(S))
    float* Spart = P + (size_t)NB * NQL * ML;         // [16][4][512] partial row sums

    dim3 gProj(NQL / 32, HDIM / 64, NB * 2);
    proj_kernel<<<gProj, 256, 0, stream>>>(query, key, Wq, Wk, EqT, EkT);

    dim3 gSc(ML / 32, NQL / 32, NB);
    scores_kernel<<<gSc, 256, 0, stream>>>(EqT, EkT, Wv, P, Spart);

    dim3 gAv(DDIM / 64, NQL / 16, NB);
    av_kernel<<<gAv, 256, 0, stream>>>(P, Spart, value, out);
}